// Round 16
// baseline (785.084 us; speedup 1.0000x reference)
//
#include <hip/hip_runtime.h>
#include <hip/hip_bf16.h>

#define B_ 2
#define N_ 16384
#define M_ 4096
#define EPS_ 1e-5f

__device__ __forceinline__ float b2f(const __hip_bfloat16 v) { return __bfloat162float(v); }

// dual-dtype input load: f32 != 0 -> buffer is float32, else bfloat16
__device__ __forceinline__ float ldin(const void* p, size_t i, int f32) {
    return f32 ? ((const float*)p)[i] : __bfloat162float(((const __hip_bfloat16*)p)[i]);
}
__device__ __forceinline__ void stout(void* o, size_t i, float v, int f32) {
    if (f32) ((float*)o)[i] = v;
    else     ((__hip_bfloat16*)o)[i] = __float2bfloat16(v);
}

// np-exact d2: dot rounded per product, sequential add; d2 = (hn+ln) - 2*dot
__device__ __forceinline__ float d2np(float x, float y, float z, float hn, float4 q) {
    float dot = __fadd_rn(__fadd_rn(__fmul_rn(x, q.x), __fmul_rn(y, q.y)), __fmul_rn(z, q.z));
    return __fsub_rn(__fadd_rn(hn, q.w), __fmul_rn(2.f, dot));
}
__device__ __forceinline__ float norm3np(float x, float y, float z) {
    return __fadd_rn(__fadd_rn(__fmul_rn(x, x), __fmul_rn(y, y)), __fmul_rn(z, z));
}

// ---------------- workspace layout ----------------
#define O_GE_W1 0
#define O_GE_B1 192
#define O_GE_W2 256
#define O_GE_B2 4352
#define O_QW    4416
#define O_QB    8512
#define O_KW    8576
#define O_KB    12672
#define O_SCW   12736
#define O_SCB   13120
#define O_SHW   13184
#define O_SHB   13568
#define O_BDW1  13632
#define O_BDB1  17728
#define O_BDW2  17792
#define O_BDB2  17856
#define O_RPW1  17920
#define O_RPB1  18112
#define O_RPW2  18176
#define O_RPB2  22272
// byte offsets of data regions (ws use ≈ 7.7 MB, proven safe since R4):
#define OB_LR    92160
#define OB_Q     223232
#define OB_KT    4417536
#define OB_VT    5466112
#define OB_KIDX  6514688
#define OB_DFLAG 7694336

#define CAP  12   // per-lane slice entries; E[cnt/lane]~0.7, P(>12) ~ 1e-12
#define CAPS 13   // slice stride (odd -> 2-way bank aliasing = free)

// ---------------- prep: dtype sniff + weights -> fp32, fold BN ----------------
__global__ __launch_bounds__(256) void prep_kernel(
    const void* xyz_hr,
    const void* ge_w1, const void* ge_b1, const void* ge_g1, const void* ge_be1,
    const void* ge_m1, const void* ge_v1, const void* ge_w2, const void* ge_b2,
    const void* sc_w, const void* sc_b, const void* sh_w, const void* sh_b,
    const void* q_w, const void* q_b, const void* k_w, const void* k_b,
    const void* bd_w1, const void* bd_b1, const void* bd_g, const void* bd_be,
    const void* bd_m, const void* bd_v, const void* bd_w2, const void* bd_b2,
    const void* rp_w1, const void* rp_b1, const void* rp_g, const void* rp_be,
    const void* rp_m, const void* rp_v, const void* rp_w2, const void* rp_b2,
    float* W, int* dflag)
{
    __shared__ int scnt;
    int t = threadIdx.x;
    if (t == 0) scnt = 0;
    __syncthreads();
    if (t < 128) {
        unsigned short u = ((const unsigned short*)xyz_hr)[t];
        int e = (u >> 7) & 0xFF;
        int ok = (e >= 113 && e <= 132) || ((u & 0x7FFF) == 0);
        if (ok) atomicAdd(&scnt, 1);
    }
    __syncthreads();
    const int f32 = (scnt < 110) ? 1 : 0;
    if (t == 0) *dflag = f32;

    if (t < 64) {
        float s = ldin(ge_g1, t, f32) * rsqrtf(ldin(ge_v1, t, f32) + EPS_);
        for (int d = 0; d < 3; ++d) W[O_GE_W1 + t*3 + d] = s * ldin(ge_w1, t*3 + d, f32);
        W[O_GE_B1 + t] = s * (ldin(ge_b1, t, f32) - ldin(ge_m1, t, f32)) + ldin(ge_be1, t, f32);
        W[O_GE_B2 + t] = ldin(ge_b2, t, f32);
        W[O_QB + t] = ldin(q_b, t, f32);
        W[O_KB + t] = ldin(k_b, t, f32);
        W[O_SCB + t] = ldin(sc_b, t, f32);
        W[O_SHB + t] = ldin(sh_b, t, f32);
        float sb = ldin(bd_g, t, f32) * rsqrtf(ldin(bd_v, t, f32) + EPS_);
        W[O_BDB1 + t] = sb * (ldin(bd_b1, t, f32) - ldin(bd_m, t, f32)) + ldin(bd_be, t, f32);
        W[O_BDW2 + t] = ldin(bd_w2, t, f32);
        float sr = ldin(rp_g, t, f32) * rsqrtf(ldin(rp_v, t, f32) + EPS_);
        for (int d = 0; d < 3; ++d) W[O_RPW1 + t*3 + d] = sr * ldin(rp_w1, t*3 + d, f32);
        W[O_RPB1 + t] = sr * (ldin(rp_b1, t, f32) - ldin(rp_m, t, f32)) + ldin(rp_be, t, f32);
        W[O_RPB2 + t] = ldin(rp_b2, t, f32);
    }
    if (t == 0) W[O_BDB2] = ldin(bd_b2, 0, f32);
    for (int i = t; i < 4096; i += 256) {
        W[O_GE_W2 + i] = ldin(ge_w2, i, f32);
        W[O_QW + i]    = ldin(q_w, i, f32);
        W[O_KW + i]    = ldin(k_w, i, f32);
        W[O_RPW2 + i]  = ldin(rp_w2, i, f32);
        int c = i >> 6;
        float sb = ldin(bd_g, c, f32) * rsqrtf(ldin(bd_v, c, f32) + EPS_);
        W[O_BDW1 + i] = sb * ldin(bd_w1, i, f32);
    }
    for (int i = t; i < 384; i += 256) {
        W[O_SCW + i] = ldin(sc_w, i, f32);
        W[O_SHW + i] = ldin(sh_w, i, f32);
    }
}

// ---------------- lr pipeline ----------------
__global__ __launch_bounds__(128, 1) void lr_kernel(
    const void* __restrict__ xyz_lr,
    const void* __restrict__ sft,
    const void* __restrict__ val,
    const float* __restrict__ W,
    __hip_bfloat16* __restrict__ Kt, __hip_bfloat16* __restrict__ Vt,
    float4* __restrict__ LR, const int* dflag)
{
    const int f32 = *dflag;
    int p = blockIdx.x * 128 + threadIdx.x;     // 0..8191
    int b = p >> 12, m = p & (M_ - 1);
    size_t base = (size_t)b*3*M_ + m;
    float x = ldin(xyz_lr, base, f32), y = ldin(xyz_lr, base + M_, f32), z = ldin(xyz_lr, base + 2*M_, f32);
    LR[p] = make_float4(x, y, z, norm3np(x, y, z));

    float h[64];
#pragma unroll
    for (int c = 0; c < 64; ++c) {
        const float* w = W + O_GE_W1 + c*3;
        h[c] = fmaxf(fmaf(w[2], z, fmaf(w[1], y, fmaf(w[0], x, W[O_GE_B1 + c]))), 0.f);
    }
    float g[64];
#pragma unroll
    for (int c = 0; c < 64; ++c) {
        float acc = W[O_GE_B2 + c];
        const float4* w4 = (const float4*)(W + O_GE_W2) + c*16;
#pragma unroll
        for (int i = 0; i < 16; ++i) {
            float4 w = w4[i];
            acc = fmaf(w.x, h[4*i+0], acc); acc = fmaf(w.y, h[4*i+1], acc);
            acc = fmaf(w.z, h[4*i+2], acc); acc = fmaf(w.w, h[4*i+3], acc);
        }
        g[c] = acc;
    }
    float s6[6];
#pragma unroll
    for (int d = 0; d < 6; ++d) s6[d] = ldin(sft, (size_t)b*6*M_ + d*M_ + m, f32);
#pragma unroll
    for (int c = 0; c < 64; ++c) {
        float sc = W[O_SCB + c], sh = W[O_SHB + c];
        const float* wsc = W + O_SCW + c*6;
        const float* wsh = W + O_SHW + c*6;
#pragma unroll
        for (int d = 0; d < 6; ++d) { sc = fmaf(wsc[d], s6[d], sc); sh = fmaf(wsh[d], s6[d], sh); }
        h[c] = fmaf(g[c], sc + 1.f, sh);   // reuse h[] as mod[]
    }
    __hip_bfloat16* kt = Kt + (size_t)p*64;
#pragma unroll
    for (int c = 0; c < 64; ++c) {
        float acc = W[O_KB + c];
        const float4* w4 = (const float4*)(W + O_KW) + c*16;
#pragma unroll
        for (int i = 0; i < 16; ++i) {
            float4 w = w4[i];
            acc = fmaf(w.x, h[4*i+0], acc); acc = fmaf(w.y, h[4*i+1], acc);
            acc = fmaf(w.z, h[4*i+2], acc); acc = fmaf(w.w, h[4*i+3], acc);
        }
        kt[c] = __float2bfloat16(acc);
    }
    __hip_bfloat16* vt = Vt + (size_t)p*64;
#pragma unroll
    for (int c = 0; c < 64; ++c) vt[c] = __float2bfloat16(ldin(val, (size_t)b*64*M_ + c*M_ + m, f32));
}

// ---------------- hr pipeline ----------------
__global__ __launch_bounds__(128, 1) void hr_kernel(
    const void* __restrict__ xyz_hr,
    const float* __restrict__ W,
    __hip_bfloat16* __restrict__ Q,
    void* __restrict__ out, const int* dflag)
{
    const int f32 = *dflag;
    int p = blockIdx.x * 128 + threadIdx.x;     // 0..32767
    int b = p >> 14, n = p & (N_ - 1);
    size_t base = (size_t)b*3*N_ + n;
    float x = ldin(xyz_hr, base, f32), y = ldin(xyz_hr, base + N_, f32), z = ldin(xyz_hr, base + 2*N_, f32);

    float h[64];
#pragma unroll
    for (int c = 0; c < 64; ++c) {
        const float* w = W + O_GE_W1 + c*3;
        h[c] = fmaxf(fmaf(w[2], z, fmaf(w[1], y, fmaf(w[0], x, W[O_GE_B1 + c]))), 0.f);
    }
    float g[64];
#pragma unroll
    for (int c = 0; c < 64; ++c) {
        float acc = W[O_GE_B2 + c];
        const float4* w4 = (const float4*)(W + O_GE_W2) + c*16;
#pragma unroll
        for (int i = 0; i < 16; ++i) {
            float4 w = w4[i];
            acc = fmaf(w.x, h[4*i+0], acc); acc = fmaf(w.y, h[4*i+1], acc);
            acc = fmaf(w.z, h[4*i+2], acc); acc = fmaf(w.w, h[4*i+3], acc);
        }
        g[c] = acc;
    }
    __hip_bfloat16* qr = Q + (size_t)p*64;
#pragma unroll
    for (int c = 0; c < 64; ++c) {
        float acc = W[O_QB + c];
        const float4* w4 = (const float4*)(W + O_QW) + c*16;
#pragma unroll
        for (int i = 0; i < 16; ++i) {
            float4 w = w4[i];
            acc = fmaf(w.x, g[4*i+0], acc); acc = fmaf(w.y, g[4*i+1], acc);
            acc = fmaf(w.z, g[4*i+2], acc); acc = fmaf(w.w, g[4*i+3], acc);
        }
        qr[c] = __float2bfloat16(acc);
    }
    float o = W[O_BDB2];
#pragma unroll
    for (int c = 0; c < 64; ++c) {
        float acc = W[O_BDB1 + c];
        const float4* w4 = (const float4*)(W + O_BDW1) + c*16;
#pragma unroll
        for (int i = 0; i < 16; ++i) {
            float4 w = w4[i];
            acc = fmaf(w.x, g[4*i+0], acc); acc = fmaf(w.y, g[4*i+1], acc);
            acc = fmaf(w.z, g[4*i+2], acc); acc = fmaf(w.w, g[4*i+3], acc);
        }
        o = fmaf(W[O_BDW2 + c], fmaxf(acc, 0.f), o);
    }
    stout(out, (size_t)B_*64*N_ + (size_t)b*N_ + n, 1.f / (1.f + __expf(-o)), f32);
}

// lexicographic (d, i) compare-exchange: keep smaller at position a
#define CE(da, ia, db, ib) { \
    bool sw_ = (db < da) || (db == da && ib < ia); \
    float td_ = da; int ti_ = ia; \
    da = sw_ ? db : da; ia = sw_ ? ib : ia; \
    db = sw_ ? td_ : db; ib = sw_ ? ti_ : ib; }

// insert (d2, m) into the sorted-16 list if it beats the tail (lex order) [proven R10]
__device__ __forceinline__ void topk_insert(float (&bd)[16], int (&bi)[16], float d2, int m) {
    if (d2 < bd[15] || (d2 == bd[15] && m < bi[15])) {
        bd[15] = d2; bi[15] = m;
#pragma unroll
        for (int j = 15; j > 0; --j) CE(bd[j-1], bi[j-1], bd[j], bi[j]);
    }
}

// ---------------- kNN: R15 selection, single-pass scan via LDS-staged LR ----------------
// R15's proven tau/slice/extract-min machinery unchanged. New: LR is staged
// through LDS in 8KB chunks ONCE per block (4 waves share the same batch's L)
// and d2 is cached in registers d2r[64], so pass 2 reads no memory at all.
// Global traffic: 512KB/block -> 512MB total (was 4.3GB of L2 re-reads).
__global__ __launch_bounds__(256) void knn_kernel(
    const void* __restrict__ xyz_hr,
    const float4* __restrict__ LR,
    unsigned short* __restrict__ kidx, const int* dflag)
{
#pragma clang fp reassociate(off)
    __shared__ float4         sLR[512];           //  8 KiB chunk of LR
    __shared__ float          sdd[256 * CAPS];    // 13.3 KiB, per-lane private d2
    __shared__ unsigned short sii[256 * CAPS];    //  6.7 KiB, per-lane private idx
    const int f32 = *dflag;
    int lane = threadIdx.x & 63;
    int p = blockIdx.x * 4 + (threadIdx.x >> 6);     // 0..32767, one point per wave
    int b = p >> 14, n = p & (N_ - 1);               // b is block-uniform (4 | 16384)
    size_t base = (size_t)b*3*N_ + n;
    float x = ldin(xyz_hr, base, f32), y = ldin(xyz_hr, base + N_, f32), z = ldin(xyz_hr, base + 2*N_, f32);
    float hn = norm3np(x, y, z);
    const float4* L = LR + b*M_;

    // pass 1: chunked LDS staging + register-cached d2; lane-local running min
    float d2r[64];
    float v = 3.4e38f;
#pragma unroll 1
    for (int c = 0; c < 8; ++c) {
        __syncthreads();
        sLR[threadIdx.x]       = L[c*512 + threadIdx.x];
        sLR[256 + threadIdx.x] = L[c*512 + 256 + threadIdx.x];
        __syncthreads();
#pragma unroll
        for (int i = 0; i < 8; ++i) {
            float d2 = d2np(x, y, z, hn, sLR[i*64 + lane]);
            d2r[c*8 + i] = d2;
            v = fminf(v, d2);
        }
    }
    // merge the 4 residues (lane, lane^16, lane^32, lane^48) -> min of class (lane&15)
    v = fminf(v, __shfl_xor(v, 16, 64));
    v = fminf(v, __shfl_xor(v, 32, 64));
    // tau = max over the 16 class minima (each 16-lane group holds all 16 classes)
    float tau = v;
#pragma unroll
    for (int st = 1; st <= 8; st <<= 1) tau = fmaxf(tau, __shfl_xor(tau, st, 64));
    // 16 distinct class argminima have d2 <= tau -> true top-16 all <= tau

    // pass 2: append candidates <= tau from REGISTERS to private slice
    int sl = threadIdx.x * CAPS;
    int cnt = 0;
#pragma unroll
    for (int i = 0; i < 64; ++i) {
        if (d2r[i] <= tau) {
            if (cnt < CAP) { sdd[sl + cnt] = d2r[i]; sii[sl + cnt] = (unsigned short)(i*64 + lane); }
            cnt++;
        }
    }
    int bad = (cnt > CAP) ? 1 : 0;
#pragma unroll
    for (int st = 1; st <= 32; st <<= 1) bad |= __shfl_xor(bad, st, 64);
    if (bad) {
        // in-wave brute-force fallback (wave-uniform branch; P ~ 1e-12)
        float bd[16]; int bi[16];
#pragma unroll
        for (int j = 0; j < 16; ++j) { bd[j] = 3.4e38f; bi[j] = 0x7fffffff; }
        for (int m = 0; m < M_; ++m) {
            topk_insert(bd, bi, d2np(x, y, z, hn, L[m]), m);
        }
        if (lane == 0) {
            unsigned short* kr = kidx + (size_t)p*16;
#pragma unroll
            for (int j = 0; j < 16; ++j) kr[j] = (unsigned short)bi[j];
        }
        return;
    }
    // selection-sort own slice (cnt <= 12, E ~0.7)
    for (int a = 0; a < cnt - 1; ++a) {
        float bv = sdd[sl + a]; int bm = (int)sii[sl + a]; int bj = a;
        for (int j2 = a + 1; j2 < cnt; ++j2) {
            float dj = sdd[sl + j2]; int mj = (int)sii[sl + j2];
            if (dj < bv || (dj == bv && mj < bm)) { bv = dj; bm = mj; bj = j2; }
        }
        float ta = sdd[sl + a]; int ia = (int)sii[sl + a];
        sdd[sl + a] = bv; sii[sl + a] = (unsigned short)bm;
        sdd[sl + bj] = ta; sii[sl + bj] = (unsigned short)ia;
    }

    // pass 3: 16 rounds of cross-lane lex extract-min on slice heads
    int ptr = 0;
    for (int r = 0; r < 16; ++r) {
        float hd = 3.4e38f; int hi = 0x7fffffff;
        if (ptr < cnt) { hd = sdd[sl + ptr]; hi = (int)sii[sl + ptr]; }
        float md = hd; int mi = hi;
#pragma unroll
        for (int st = 1; st <= 32; st <<= 1) {
            float od = __shfl_xor(md, st, 64);
            int   oi = __shfl_xor(mi, st, 64);
            bool s = (od < md) || (od == md && oi < mi);
            md = s ? od : md; mi = s ? oi : mi;
        }
        if (ptr < cnt && hi == mi) {           // unique winner (indices unique)
            kidx[(size_t)p*16 + r] = (unsigned short)mi;
            ptr++;
        }
    }
}

// ---------------- attention: one point per wave, lane = channel ----------------
// logit_j = [Q.K_j + (W2^T Q).pe_j]/8; the j-invariant Q.b2 cancels in softmax.
__global__ __launch_bounds__(256) void attn_kernel(
    const void* __restrict__ xyz_hr,
    const float4* __restrict__ LR,
    const float* __restrict__ W,
    const __hip_bfloat16* __restrict__ Q,
    const __hip_bfloat16* __restrict__ Kt,
    const __hip_bfloat16* __restrict__ Vt,
    const unsigned short* __restrict__ kidx,
    void* __restrict__ out, const int* dflag)
{
    const int f32 = *dflag;
    int p = (blockIdx.x * 256 + threadIdx.x) >> 6;     // 0..32767, one point per wave
    int lane = threadIdx.x & 63;
    float fw0 = W[O_RPW1 + lane*3], fw1 = W[O_RPW1 + lane*3 + 1], fw2 = W[O_RPW1 + lane*3 + 2];
    float fb  = W[O_RPB1 + lane];

    int b = p >> 14, n = p & (N_ - 1);
    size_t base = (size_t)b*3*N_ + n;
    float xh = ldin(xyz_hr, base, f32), yh = ldin(xyz_hr, base + N_, f32), zh = ldin(xyz_hr, base + 2*N_, f32);
    float qc = b2f(Q[(size_t)p*64 + lane]);
    // q2_lane = sum_c Q_c * W2[c][lane]
    float q2 = 0.f;
#pragma unroll
    for (int cc = 0; cc < 64; ++cc) {
        float qb = __shfl(qc, cc, 64);
        q2 = fmaf(W[O_RPW2 + cc*64 + lane], qb, q2);
    }
    int idxv = (int)kidx[(size_t)p*16 + (lane & 15)];
    const float4* L = LR + b*M_;
    const __hip_bfloat16* Ktb = Kt + (size_t)b*M_*64;
    const __hip_bfloat16* Vtb = Vt + (size_t)b*M_*64;
    float lg[16];
#pragma unroll
    for (int j = 0; j < 16; ++j) {
        int mj = __shfl(idxv, j, 64);
        mj = (mj < M_) ? mj : (M_ - 1);
        float4 pl = L[mj];
        float r0 = xh - pl.x, r1 = yh - pl.y, r2 = zh - pl.z;
        float pe = fmaxf(fmaf(fw2, r2, fmaf(fw1, r1, fmaf(fw0, r0, fb))), 0.f);
        float v = fmaf(qc, b2f(Ktb[(size_t)mj*64 + lane]), q2 * pe);
#pragma unroll
        for (int sh = 1; sh < 64; sh <<= 1) v += __shfl_xor(v, sh, 64);
        lg[j] = v * 0.125f;
    }
    float mx = lg[0];
#pragma unroll
    for (int j = 1; j < 16; ++j) mx = fmaxf(mx, lg[j]);
    float sum = 0.f;
#pragma unroll
    for (int j = 0; j < 16; ++j) { lg[j] = __expf(lg[j] - mx); sum += lg[j]; }
    float inv = 1.f / sum;
    float o = 0.f;
#pragma unroll
    for (int j = 0; j < 16; ++j) {
        int mj = __shfl(idxv, j, 64);
        mj = (mj < M_) ? mj : (M_ - 1);
        o = fmaf(lg[j] * inv, b2f(Vtb[(size_t)mj*64 + lane]), o);
    }
    stout(out, ((size_t)(b*64 + lane))*N_ + n, o, f32);
}

// ---------------- launch ----------------
extern "C" void kernel_launch(void* const* d_in, const int* in_sizes, int n_in,
                              void* d_out, int out_size, void* d_ws, size_t ws_size,
                              hipStream_t stream) {
    const void* xyz_hr = d_in[0];
    const void* xyz_lr = d_in[1];
    const void* sft    = d_in[2];
    const void* val    = d_in[3];

    char* ws = (char*)d_ws;
    float* W  = (float*)ws;
    float4* LR = (float4*)(ws + OB_LR);
    __hip_bfloat16* Qp = (__hip_bfloat16*)(ws + OB_Q);
    __hip_bfloat16* Kt = (__hip_bfloat16*)(ws + OB_KT);
    __hip_bfloat16* Vt = (__hip_bfloat16*)(ws + OB_VT);
    unsigned short* kidx = (unsigned short*)(ws + OB_KIDX);
    int* dflag = (int*)(ws + OB_DFLAG);

    prep_kernel<<<1, 256, 0, stream>>>(
        xyz_hr,
        d_in[4],  d_in[5],  d_in[6],  d_in[7],  d_in[8],  d_in[9],  d_in[10], d_in[11],
        d_in[12], d_in[13], d_in[14], d_in[15], d_in[16], d_in[17], d_in[18], d_in[19],
        d_in[20], d_in[21], d_in[22], d_in[23], d_in[24], d_in[25], d_in[26], d_in[27],
        d_in[28], d_in[29], d_in[30], d_in[31], d_in[32], d_in[33], d_in[34], d_in[35],
        W, dflag);
    lr_kernel<<<64, 128, 0, stream>>>(xyz_lr, sft, val, W, Kt, Vt, LR, dflag);
    hr_kernel<<<256, 128, 0, stream>>>(xyz_hr, W, Qp, d_out, dflag);
    knn_kernel<<<8192, 256, 0, stream>>>(xyz_hr, LR, kidx, dflag);
    attn_kernel<<<8192, 256, 0, stream>>>(xyz_hr, LR, W, Qp, Kt, Vt, kidx, d_out, dflag);
}

// Round 17
// 631.952 us; speedup vs baseline: 1.2423x; 1.2423x over previous
//
#include <hip/hip_runtime.h>
#include <hip/hip_bf16.h>

#define B_ 2
#define N_ 16384
#define M_ 4096
#define EPS_ 1e-5f

__device__ __forceinline__ float b2f(const __hip_bfloat16 v) { return __bfloat162float(v); }

// dual-dtype input load: f32 != 0 -> buffer is float32, else bfloat16
__device__ __forceinline__ float ldin(const void* p, size_t i, int f32) {
    return f32 ? ((const float*)p)[i] : __bfloat162float(((const __hip_bfloat16*)p)[i]);
}
__device__ __forceinline__ void stout(void* o, size_t i, float v, int f32) {
    if (f32) ((float*)o)[i] = v;
    else     ((__hip_bfloat16*)o)[i] = __float2bfloat16(v);
}

// np-exact d2: dot rounded per product, sequential add; d2 = (hn+ln) - 2*dot
__device__ __forceinline__ float d2np(float x, float y, float z, float hn, float4 q) {
    float dot = __fadd_rn(__fadd_rn(__fmul_rn(x, q.x), __fmul_rn(y, q.y)), __fmul_rn(z, q.z));
    return __fsub_rn(__fadd_rn(hn, q.w), __fmul_rn(2.f, dot));
}
__device__ __forceinline__ float norm3np(float x, float y, float z) {
    return __fadd_rn(__fadd_rn(__fmul_rn(x, x), __fmul_rn(y, y)), __fmul_rn(z, z));
}

// ---------------- workspace layout ----------------
#define O_GE_W1 0
#define O_GE_B1 192
#define O_GE_W2 256
#define O_GE_B2 4352
#define O_QW    4416
#define O_QB    8512
#define O_KW    8576
#define O_KB    12672
#define O_SCW   12736
#define O_SCB   13120
#define O_SHW   13184
#define O_SHB   13568
#define O_BDW1  13632
#define O_BDB1  17728
#define O_BDW2  17792
#define O_BDB2  17856
#define O_RPW1  17920
#define O_RPB1  18112
#define O_RPW2  18176
#define O_RPB2  22272
// byte offsets of data regions (ws use ≈ 7.7 MB, proven safe since R4):
#define OB_LR    92160
#define OB_Q     223232
#define OB_KT    4417536
#define OB_VT    5466112
#define OB_KIDX  6514688
#define OB_DFLAG 7694336

#define CAP  12   // per-lane slice entries; E[cnt/lane]~0.7, P(>12) ~ 1e-12
#define CAPS 13   // slice stride (odd -> 2-way bank aliasing = free)

// ---------------- prep: dtype sniff + weights -> fp32, fold BN ----------------
__global__ __launch_bounds__(256) void prep_kernel(
    const void* xyz_hr,
    const void* ge_w1, const void* ge_b1, const void* ge_g1, const void* ge_be1,
    const void* ge_m1, const void* ge_v1, const void* ge_w2, const void* ge_b2,
    const void* sc_w, const void* sc_b, const void* sh_w, const void* sh_b,
    const void* q_w, const void* q_b, const void* k_w, const void* k_b,
    const void* bd_w1, const void* bd_b1, const void* bd_g, const void* bd_be,
    const void* bd_m, const void* bd_v, const void* bd_w2, const void* bd_b2,
    const void* rp_w1, const void* rp_b1, const void* rp_g, const void* rp_be,
    const void* rp_m, const void* rp_v, const void* rp_w2, const void* rp_b2,
    float* W, int* dflag)
{
    __shared__ int scnt;
    int t = threadIdx.x;
    if (t == 0) scnt = 0;
    __syncthreads();
    if (t < 128) {
        unsigned short u = ((const unsigned short*)xyz_hr)[t];
        int e = (u >> 7) & 0xFF;
        int ok = (e >= 113 && e <= 132) || ((u & 0x7FFF) == 0);
        if (ok) atomicAdd(&scnt, 1);
    }
    __syncthreads();
    const int f32 = (scnt < 110) ? 1 : 0;
    if (t == 0) *dflag = f32;

    if (t < 64) {
        float s = ldin(ge_g1, t, f32) * rsqrtf(ldin(ge_v1, t, f32) + EPS_);
        for (int d = 0; d < 3; ++d) W[O_GE_W1 + t*3 + d] = s * ldin(ge_w1, t*3 + d, f32);
        W[O_GE_B1 + t] = s * (ldin(ge_b1, t, f32) - ldin(ge_m1, t, f32)) + ldin(ge_be1, t, f32);
        W[O_GE_B2 + t] = ldin(ge_b2, t, f32);
        W[O_QB + t] = ldin(q_b, t, f32);
        W[O_KB + t] = ldin(k_b, t, f32);
        W[O_SCB + t] = ldin(sc_b, t, f32);
        W[O_SHB + t] = ldin(sh_b, t, f32);
        float sb = ldin(bd_g, t, f32) * rsqrtf(ldin(bd_v, t, f32) + EPS_);
        W[O_BDB1 + t] = sb * (ldin(bd_b1, t, f32) - ldin(bd_m, t, f32)) + ldin(bd_be, t, f32);
        W[O_BDW2 + t] = ldin(bd_w2, t, f32);
        float sr = ldin(rp_g, t, f32) * rsqrtf(ldin(rp_v, t, f32) + EPS_);
        for (int d = 0; d < 3; ++d) W[O_RPW1 + t*3 + d] = sr * ldin(rp_w1, t*3 + d, f32);
        W[O_RPB1 + t] = sr * (ldin(rp_b1, t, f32) - ldin(rp_m, t, f32)) + ldin(rp_be, t, f32);
        W[O_RPB2 + t] = ldin(rp_b2, t, f32);
    }
    if (t == 0) W[O_BDB2] = ldin(bd_b2, 0, f32);
    for (int i = t; i < 4096; i += 256) {
        W[O_GE_W2 + i] = ldin(ge_w2, i, f32);
        W[O_QW + i]    = ldin(q_w, i, f32);
        W[O_KW + i]    = ldin(k_w, i, f32);
        W[O_RPW2 + i]  = ldin(rp_w2, i, f32);
        int c = i >> 6;
        float sb = ldin(bd_g, c, f32) * rsqrtf(ldin(bd_v, c, f32) + EPS_);
        W[O_BDW1 + i] = sb * ldin(bd_w1, i, f32);
    }
    for (int i = t; i < 384; i += 256) {
        W[O_SCW + i] = ldin(sc_w, i, f32);
        W[O_SHW + i] = ldin(sh_w, i, f32);
    }
}

// ---------------- lr pipeline ----------------
__global__ __launch_bounds__(128, 1) void lr_kernel(
    const void* __restrict__ xyz_lr,
    const void* __restrict__ sft,
    const void* __restrict__ val,
    const float* __restrict__ W,
    __hip_bfloat16* __restrict__ Kt, __hip_bfloat16* __restrict__ Vt,
    float4* __restrict__ LR, const int* dflag)
{
    const int f32 = *dflag;
    int p = blockIdx.x * 128 + threadIdx.x;     // 0..8191
    int b = p >> 12, m = p & (M_ - 1);
    size_t base = (size_t)b*3*M_ + m;
    float x = ldin(xyz_lr, base, f32), y = ldin(xyz_lr, base + M_, f32), z = ldin(xyz_lr, base + 2*M_, f32);
    LR[p] = make_float4(x, y, z, norm3np(x, y, z));

    float h[64];
#pragma unroll
    for (int c = 0; c < 64; ++c) {
        const float* w = W + O_GE_W1 + c*3;
        h[c] = fmaxf(fmaf(w[2], z, fmaf(w[1], y, fmaf(w[0], x, W[O_GE_B1 + c]))), 0.f);
    }
    float g[64];
#pragma unroll
    for (int c = 0; c < 64; ++c) {
        float acc = W[O_GE_B2 + c];
        const float4* w4 = (const float4*)(W + O_GE_W2) + c*16;
#pragma unroll
        for (int i = 0; i < 16; ++i) {
            float4 w = w4[i];
            acc = fmaf(w.x, h[4*i+0], acc); acc = fmaf(w.y, h[4*i+1], acc);
            acc = fmaf(w.z, h[4*i+2], acc); acc = fmaf(w.w, h[4*i+3], acc);
        }
        g[c] = acc;
    }
    float s6[6];
#pragma unroll
    for (int d = 0; d < 6; ++d) s6[d] = ldin(sft, (size_t)b*6*M_ + d*M_ + m, f32);
#pragma unroll
    for (int c = 0; c < 64; ++c) {
        float sc = W[O_SCB + c], sh = W[O_SHB + c];
        const float* wsc = W + O_SCW + c*6;
        const float* wsh = W + O_SHW + c*6;
#pragma unroll
        for (int d = 0; d < 6; ++d) { sc = fmaf(wsc[d], s6[d], sc); sh = fmaf(wsh[d], s6[d], sh); }
        h[c] = fmaf(g[c], sc + 1.f, sh);   // reuse h[] as mod[]
    }
    __hip_bfloat16* kt = Kt + (size_t)p*64;
#pragma unroll
    for (int c = 0; c < 64; ++c) {
        float acc = W[O_KB + c];
        const float4* w4 = (const float4*)(W + O_KW) + c*16;
#pragma unroll
        for (int i = 0; i < 16; ++i) {
            float4 w = w4[i];
            acc = fmaf(w.x, h[4*i+0], acc); acc = fmaf(w.y, h[4*i+1], acc);
            acc = fmaf(w.z, h[4*i+2], acc); acc = fmaf(w.w, h[4*i+3], acc);
        }
        kt[c] = __float2bfloat16(acc);
    }
    __hip_bfloat16* vt = Vt + (size_t)p*64;
#pragma unroll
    for (int c = 0; c < 64; ++c) vt[c] = __float2bfloat16(ldin(val, (size_t)b*64*M_ + c*M_ + m, f32));
}

// ---------------- hr pipeline ----------------
__global__ __launch_bounds__(128, 1) void hr_kernel(
    const void* __restrict__ xyz_hr,
    const float* __restrict__ W,
    __hip_bfloat16* __restrict__ Q,
    void* __restrict__ out, const int* dflag)
{
    const int f32 = *dflag;
    int p = blockIdx.x * 128 + threadIdx.x;     // 0..32767
    int b = p >> 14, n = p & (N_ - 1);
    size_t base = (size_t)b*3*N_ + n;
    float x = ldin(xyz_hr, base, f32), y = ldin(xyz_hr, base + N_, f32), z = ldin(xyz_hr, base + 2*N_, f32);

    float h[64];
#pragma unroll
    for (int c = 0; c < 64; ++c) {
        const float* w = W + O_GE_W1 + c*3;
        h[c] = fmaxf(fmaf(w[2], z, fmaf(w[1], y, fmaf(w[0], x, W[O_GE_B1 + c]))), 0.f);
    }
    float g[64];
#pragma unroll
    for (int c = 0; c < 64; ++c) {
        float acc = W[O_GE_B2 + c];
        const float4* w4 = (const float4*)(W + O_GE_W2) + c*16;
#pragma unroll
        for (int i = 0; i < 16; ++i) {
            float4 w = w4[i];
            acc = fmaf(w.x, h[4*i+0], acc); acc = fmaf(w.y, h[4*i+1], acc);
            acc = fmaf(w.z, h[4*i+2], acc); acc = fmaf(w.w, h[4*i+3], acc);
        }
        g[c] = acc;
    }
    __hip_bfloat16* qr = Q + (size_t)p*64;
#pragma unroll
    for (int c = 0; c < 64; ++c) {
        float acc = W[O_QB + c];
        const float4* w4 = (const float4*)(W + O_QW) + c*16;
#pragma unroll
        for (int i = 0; i < 16; ++i) {
            float4 w = w4[i];
            acc = fmaf(w.x, g[4*i+0], acc); acc = fmaf(w.y, g[4*i+1], acc);
            acc = fmaf(w.z, g[4*i+2], acc); acc = fmaf(w.w, g[4*i+3], acc);
        }
        qr[c] = __float2bfloat16(acc);
    }
    float o = W[O_BDB2];
#pragma unroll
    for (int c = 0; c < 64; ++c) {
        float acc = W[O_BDB1 + c];
        const float4* w4 = (const float4*)(W + O_BDW1) + c*16;
#pragma unroll
        for (int i = 0; i < 16; ++i) {
            float4 w = w4[i];
            acc = fmaf(w.x, g[4*i+0], acc); acc = fmaf(w.y, g[4*i+1], acc);
            acc = fmaf(w.z, g[4*i+2], acc); acc = fmaf(w.w, g[4*i+3], acc);
        }
        o = fmaf(W[O_BDW2 + c], fmaxf(acc, 0.f), o);
    }
    stout(out, (size_t)B_*64*N_ + (size_t)b*N_ + n, 1.f / (1.f + __expf(-o)), f32);
}

// lexicographic (d, i) compare-exchange: keep smaller at position a
#define CE(da, ia, db, ib) { \
    bool sw_ = (db < da) || (db == da && ib < ia); \
    float td_ = da; int ti_ = ia; \
    da = sw_ ? db : da; ia = sw_ ? ib : ia; \
    db = sw_ ? td_ : db; ib = sw_ ? ti_ : ib; }

// insert (d2, m) into the sorted-16 list if it beats the tail (lex order) [proven R10]
__device__ __forceinline__ void topk_insert(float (&bd)[16], int (&bi)[16], float d2, int m) {
    if (d2 < bd[15] || (d2 == bd[15] && m < bi[15])) {
        bd[15] = d2; bi[15] = m;
#pragma unroll
        for (int j = 15; j > 0; --j) CE(bd[j-1], bi[j-1], bd[j], bi[j]);
    }
}

// ---------------- kNN: R15 selection, single-pass scan via LDS-staged LR ----------------
// R16 structure with the spill fixed: the chunk loop is FULLY UNROLLED so all
// d2r[] indices are compile-time constants -> d2r lives in 64 VGPRs (R16's
// "#pragma unroll 1" made the index dynamic -> scratch -> 1GB of HBM spill,
// VGPR_Count=44 was the tell). lb(256,2) raises the VGPR cap to fit it.
__global__ __launch_bounds__(256, 2) void knn_kernel(
    const void* __restrict__ xyz_hr,
    const float4* __restrict__ LR,
    unsigned short* __restrict__ kidx, const int* dflag)
{
#pragma clang fp reassociate(off)
    __shared__ float4         sLR[512];           //  8 KiB chunk of LR
    __shared__ float          sdd[256 * CAPS];    // 13.3 KiB, per-lane private d2
    __shared__ unsigned short sii[256 * CAPS];    //  6.7 KiB, per-lane private idx
    const int f32 = *dflag;
    int lane = threadIdx.x & 63;
    int p = blockIdx.x * 4 + (threadIdx.x >> 6);     // 0..32767, one point per wave
    int b = p >> 14, n = p & (N_ - 1);               // b is block-uniform (4 | 16384)
    size_t base = (size_t)b*3*N_ + n;
    float x = ldin(xyz_hr, base, f32), y = ldin(xyz_hr, base + N_, f32), z = ldin(xyz_hr, base + 2*N_, f32);
    float hn = norm3np(x, y, z);
    const float4* L = LR + b*M_;

    // pass 1: chunked LDS staging + register-cached d2; lane-local running min.
    // FULLY unrolled -> d2r indices static -> registers.
    float d2r[64];
    float v = 3.4e38f;
#pragma unroll
    for (int c = 0; c < 8; ++c) {
        __syncthreads();
        sLR[threadIdx.x]       = L[c*512 + threadIdx.x];
        sLR[256 + threadIdx.x] = L[c*512 + 256 + threadIdx.x];
        __syncthreads();
#pragma unroll
        for (int i = 0; i < 8; ++i) {
            float d2 = d2np(x, y, z, hn, sLR[i*64 + lane]);
            d2r[c*8 + i] = d2;
            v = fminf(v, d2);
        }
    }
    // merge the 4 residues (lane, lane^16, lane^32, lane^48) -> min of class (lane&15)
    v = fminf(v, __shfl_xor(v, 16, 64));
    v = fminf(v, __shfl_xor(v, 32, 64));
    // tau = max over the 16 class minima (each 16-lane group holds all 16 classes)
    float tau = v;
#pragma unroll
    for (int st = 1; st <= 8; st <<= 1) tau = fmaxf(tau, __shfl_xor(tau, st, 64));
    // 16 distinct class argminima have d2 <= tau -> true top-16 all <= tau

    // pass 2: append candidates <= tau from REGISTERS to private slice
    int sl = threadIdx.x * CAPS;
    int cnt = 0;
#pragma unroll
    for (int i = 0; i < 64; ++i) {
        if (d2r[i] <= tau) {
            if (cnt < CAP) { sdd[sl + cnt] = d2r[i]; sii[sl + cnt] = (unsigned short)(i*64 + lane); }
            cnt++;
        }
    }
    int bad = (cnt > CAP) ? 1 : 0;
#pragma unroll
    for (int st = 1; st <= 32; st <<= 1) bad |= __shfl_xor(bad, st, 64);
    if (bad) {
        // in-wave brute-force fallback (wave-uniform branch; P ~ 1e-12)
        float bd[16]; int bi[16];
#pragma unroll
        for (int j = 0; j < 16; ++j) { bd[j] = 3.4e38f; bi[j] = 0x7fffffff; }
        for (int m = 0; m < M_; ++m) {
            topk_insert(bd, bi, d2np(x, y, z, hn, L[m]), m);
        }
        if (lane == 0) {
            unsigned short* kr = kidx + (size_t)p*16;
#pragma unroll
            for (int j = 0; j < 16; ++j) kr[j] = (unsigned short)bi[j];
        }
        return;
    }
    // selection-sort own slice (cnt <= 12, E ~0.7)
    for (int a = 0; a < cnt - 1; ++a) {
        float bv = sdd[sl + a]; int bm = (int)sii[sl + a]; int bj = a;
        for (int j2 = a + 1; j2 < cnt; ++j2) {
            float dj = sdd[sl + j2]; int mj = (int)sii[sl + j2];
            if (dj < bv || (dj == bv && mj < bm)) { bv = dj; bm = mj; bj = j2; }
        }
        float ta = sdd[sl + a]; int ia = (int)sii[sl + a];
        sdd[sl + a] = bv; sii[sl + a] = (unsigned short)bm;
        sdd[sl + bj] = ta; sii[sl + bj] = (unsigned short)ia;
    }

    // pass 3: 16 rounds of cross-lane lex extract-min on slice heads
    int ptr = 0;
    for (int r = 0; r < 16; ++r) {
        float hd = 3.4e38f; int hi = 0x7fffffff;
        if (ptr < cnt) { hd = sdd[sl + ptr]; hi = (int)sii[sl + ptr]; }
        float md = hd; int mi = hi;
#pragma unroll
        for (int st = 1; st <= 32; st <<= 1) {
            float od = __shfl_xor(md, st, 64);
            int   oi = __shfl_xor(mi, st, 64);
            bool s = (od < md) || (od == md && oi < mi);
            md = s ? od : md; mi = s ? oi : mi;
        }
        if (ptr < cnt && hi == mi) {           // unique winner (indices unique)
            kidx[(size_t)p*16 + r] = (unsigned short)mi;
            ptr++;
        }
    }
}

// ---------------- attention: one point per wave, lane = channel ----------------
// logit_j = [Q.K_j + (W2^T Q).pe_j]/8; the j-invariant Q.b2 cancels in softmax.
__global__ __launch_bounds__(256) void attn_kernel(
    const void* __restrict__ xyz_hr,
    const float4* __restrict__ LR,
    const float* __restrict__ W,
    const __hip_bfloat16* __restrict__ Q,
    const __hip_bfloat16* __restrict__ Kt,
    const __hip_bfloat16* __restrict__ Vt,
    const unsigned short* __restrict__ kidx,
    void* __restrict__ out, const int* dflag)
{
    const int f32 = *dflag;
    int p = (blockIdx.x * 256 + threadIdx.x) >> 6;     // 0..32767, one point per wave
    int lane = threadIdx.x & 63;
    float fw0 = W[O_RPW1 + lane*3], fw1 = W[O_RPW1 + lane*3 + 1], fw2 = W[O_RPW1 + lane*3 + 2];
    float fb  = W[O_RPB1 + lane];

    int b = p >> 14, n = p & (N_ - 1);
    size_t base = (size_t)b*3*N_ + n;
    float xh = ldin(xyz_hr, base, f32), yh = ldin(xyz_hr, base + N_, f32), zh = ldin(xyz_hr, base + 2*N_, f32);
    float qc = b2f(Q[(size_t)p*64 + lane]);
    // q2_lane = sum_c Q_c * W2[c][lane]
    float q2 = 0.f;
#pragma unroll
    for (int cc = 0; cc < 64; ++cc) {
        float qb = __shfl(qc, cc, 64);
        q2 = fmaf(W[O_RPW2 + cc*64 + lane], qb, q2);
    }
    int idxv = (int)kidx[(size_t)p*16 + (lane & 15)];
    const float4* L = LR + b*M_;
    const __hip_bfloat16* Ktb = Kt + (size_t)b*M_*64;
    const __hip_bfloat16* Vtb = Vt + (size_t)b*M_*64;
    float lg[16];
#pragma unroll
    for (int j = 0; j < 16; ++j) {
        int mj = __shfl(idxv, j, 64);
        mj = (mj < M_) ? mj : (M_ - 1);
        float4 pl = L[mj];
        float r0 = xh - pl.x, r1 = yh - pl.y, r2 = zh - pl.z;
        float pe = fmaxf(fmaf(fw2, r2, fmaf(fw1, r1, fmaf(fw0, r0, fb))), 0.f);
        float v = fmaf(qc, b2f(Ktb[(size_t)mj*64 + lane]), q2 * pe);
#pragma unroll
        for (int sh = 1; sh < 64; sh <<= 1) v += __shfl_xor(v, sh, 64);
        lg[j] = v * 0.125f;
    }
    float mx = lg[0];
#pragma unroll
    for (int j = 1; j < 16; ++j) mx = fmaxf(mx, lg[j]);
    float sum = 0.f;
#pragma unroll
    for (int j = 0; j < 16; ++j) { lg[j] = __expf(lg[j] - mx); sum += lg[j]; }
    float inv = 1.f / sum;
    float o = 0.f;
#pragma unroll
    for (int j = 0; j < 16; ++j) {
        int mj = __shfl(idxv, j, 64);
        mj = (mj < M_) ? mj : (M_ - 1);
        o = fmaf(lg[j] * inv, b2f(Vtb[(size_t)mj*64 + lane]), o);
    }
    stout(out, ((size_t)(b*64 + lane))*N_ + n, o, f32);
}

// ---------------- launch ----------------
extern "C" void kernel_launch(void* const* d_in, const int* in_sizes, int n_in,
                              void* d_out, int out_size, void* d_ws, size_t ws_size,
                              hipStream_t stream) {
    const void* xyz_hr = d_in[0];
    const void* xyz_lr = d_in[1];
    const void* sft    = d_in[2];
    const void* val    = d_in[3];

    char* ws = (char*)d_ws;
    float* W  = (float*)ws;
    float4* LR = (float4*)(ws + OB_LR);
    __hip_bfloat16* Qp = (__hip_bfloat16*)(ws + OB_Q);
    __hip_bfloat16* Kt = (__hip_bfloat16*)(ws + OB_KT);
    __hip_bfloat16* Vt = (__hip_bfloat16*)(ws + OB_VT);
    unsigned short* kidx = (unsigned short*)(ws + OB_KIDX);
    int* dflag = (int*)(ws + OB_DFLAG);

    prep_kernel<<<1, 256, 0, stream>>>(
        xyz_hr,
        d_in[4],  d_in[5],  d_in[6],  d_in[7],  d_in[8],  d_in[9],  d_in[10], d_in[11],
        d_in[12], d_in[13], d_in[14], d_in[15], d_in[16], d_in[17], d_in[18], d_in[19],
        d_in[20], d_in[21], d_in[22], d_in[23], d_in[24], d_in[25], d_in[26], d_in[27],
        d_in[28], d_in[29], d_in[30], d_in[31], d_in[32], d_in[33], d_in[34], d_in[35],
        W, dflag);
    lr_kernel<<<64, 128, 0, stream>>>(xyz_lr, sft, val, W, Kt, Vt, LR, dflag);
    hr_kernel<<<256, 128, 0, stream>>>(xyz_hr, W, Qp, d_out, dflag);
    knn_kernel<<<8192, 256, 0, stream>>>(xyz_hr, LR, kidx, dflag);
    attn_kernel<<<8192, 256, 0, stream>>>(xyz_hr, LR, W, Qp, Kt, Vt, kidx, d_out, dflag);
}

// Round 18
// 425.921 us; speedup vs baseline: 1.8433x; 1.4837x over previous
//
#include <hip/hip_runtime.h>
#include <hip/hip_bf16.h>

#define B_ 2
#define N_ 16384
#define M_ 4096
#define EPS_ 1e-5f

__device__ __forceinline__ float b2f(const __hip_bfloat16 v) { return __bfloat162float(v); }

// dual-dtype input load: f32 != 0 -> buffer is float32, else bfloat16
__device__ __forceinline__ float ldin(const void* p, size_t i, int f32) {
    return f32 ? ((const float*)p)[i] : __bfloat162float(((const __hip_bfloat16*)p)[i]);
}
__device__ __forceinline__ void stout(void* o, size_t i, float v, int f32) {
    if (f32) ((float*)o)[i] = v;
    else     ((__hip_bfloat16*)o)[i] = __float2bfloat16(v);
}

// np-exact d2: dot rounded per product, sequential add; d2 = (hn+ln) - 2*dot
__device__ __forceinline__ float d2np(float x, float y, float z, float hn, float4 q) {
    float dot = __fadd_rn(__fadd_rn(__fmul_rn(x, q.x), __fmul_rn(y, q.y)), __fmul_rn(z, q.z));
    return __fsub_rn(__fadd_rn(hn, q.w), __fmul_rn(2.f, dot));
}
__device__ __forceinline__ float norm3np(float x, float y, float z) {
    return __fadd_rn(__fadd_rn(__fmul_rn(x, x), __fmul_rn(y, y)), __fmul_rn(z, z));
}

// ---------------- workspace layout ----------------
#define O_GE_W1 0
#define O_GE_B1 192
#define O_GE_W2 256
#define O_GE_B2 4352
#define O_QW    4416
#define O_QB    8512
#define O_KW    8576
#define O_KB    12672
#define O_SCW   12736
#define O_SCB   13120
#define O_SHW   13184
#define O_SHB   13568
#define O_BDW1  13632
#define O_BDB1  17728
#define O_BDW2  17792
#define O_BDB2  17856
#define O_RPW1  17920
#define O_RPB1  18112
#define O_RPW2  18176
#define O_RPB2  22272
// byte offsets of data regions (≈7.7 MB proven safe since R4):
#define OB_LR    92160
#define OB_Q     223232
#define OB_KT    4417536
#define OB_VT    5466112
#define OB_KIDX  6514688
#define OB_DFLAG 7694336
// transposed weights (float offsets from ws base): WT[i][c] = Wrow[c][i]
// 4 x 16 KB appended after OB_DFLAG; ws use ends at 7.76 MB.
#define O_T_GE_W2 1923840
#define O_T_QW    1927936
#define O_T_KW    1932032
#define O_T_BDW1  1936128

#define CAP  12   // per-lane slice entries; E[cnt/lane]~0.7, P(>12) ~ 1e-12
#define CAPS 13   // slice stride (odd -> 2-way bank aliasing = free)

// ---------------- prep: dtype sniff + weights -> fp32 (+transposes), fold BN ----------------
__global__ __launch_bounds__(256) void prep_kernel(
    const void* xyz_hr,
    const void* ge_w1, const void* ge_b1, const void* ge_g1, const void* ge_be1,
    const void* ge_m1, const void* ge_v1, const void* ge_w2, const void* ge_b2,
    const void* sc_w, const void* sc_b, const void* sh_w, const void* sh_b,
    const void* q_w, const void* q_b, const void* k_w, const void* k_b,
    const void* bd_w1, const void* bd_b1, const void* bd_g, const void* bd_be,
    const void* bd_m, const void* bd_v, const void* bd_w2, const void* bd_b2,
    const void* rp_w1, const void* rp_b1, const void* rp_g, const void* rp_be,
    const void* rp_m, const void* rp_v, const void* rp_w2, const void* rp_b2,
    float* W, int* dflag)
{
    __shared__ int scnt;
    int t = threadIdx.x;
    if (t == 0) scnt = 0;
    __syncthreads();
    if (t < 128) {
        unsigned short u = ((const unsigned short*)xyz_hr)[t];
        int e = (u >> 7) & 0xFF;
        int ok = (e >= 113 && e <= 132) || ((u & 0x7FFF) == 0);
        if (ok) atomicAdd(&scnt, 1);
    }
    __syncthreads();
    const int f32 = (scnt < 110) ? 1 : 0;
    if (t == 0) *dflag = f32;

    if (t < 64) {
        float s = ldin(ge_g1, t, f32) * rsqrtf(ldin(ge_v1, t, f32) + EPS_);
        for (int d = 0; d < 3; ++d) W[O_GE_W1 + t*3 + d] = s * ldin(ge_w1, t*3 + d, f32);
        W[O_GE_B1 + t] = s * (ldin(ge_b1, t, f32) - ldin(ge_m1, t, f32)) + ldin(ge_be1, t, f32);
        W[O_GE_B2 + t] = ldin(ge_b2, t, f32);
        W[O_QB + t] = ldin(q_b, t, f32);
        W[O_KB + t] = ldin(k_b, t, f32);
        W[O_SCB + t] = ldin(sc_b, t, f32);
        W[O_SHB + t] = ldin(sh_b, t, f32);
        float sb = ldin(bd_g, t, f32) * rsqrtf(ldin(bd_v, t, f32) + EPS_);
        W[O_BDB1 + t] = sb * (ldin(bd_b1, t, f32) - ldin(bd_m, t, f32)) + ldin(bd_be, t, f32);
        W[O_BDW2 + t] = ldin(bd_w2, t, f32);
        float sr = ldin(rp_g, t, f32) * rsqrtf(ldin(rp_v, t, f32) + EPS_);
        for (int d = 0; d < 3; ++d) W[O_RPW1 + t*3 + d] = sr * ldin(rp_w1, t*3 + d, f32);
        W[O_RPB1 + t] = sr * (ldin(rp_b1, t, f32) - ldin(rp_m, t, f32)) + ldin(rp_be, t, f32);
        W[O_RPB2 + t] = ldin(rp_b2, t, f32);
    }
    if (t == 0) W[O_BDB2] = ldin(bd_b2, 0, f32);
    for (int i = t; i < 4096; i += 256) {
        int c = i >> 6, r = i & 63;        // row (output ch), col (input ch)
        float w2 = ldin(ge_w2, i, f32);
        float qw = ldin(q_w, i, f32);
        float kw = ldin(k_w, i, f32);
        float sb = ldin(bd_g, c, f32) * rsqrtf(ldin(bd_v, c, f32) + EPS_);
        float bw = sb * ldin(bd_w1, i, f32);
        W[O_GE_W2 + i] = w2;
        W[O_QW + i]    = qw;
        W[O_KW + i]    = kw;
        W[O_RPW2 + i]  = ldin(rp_w2, i, f32);
        W[O_BDW1 + i]  = bw;
        // transposed copies: WT[r*64 + c] = Wrow[c][r]
        W[O_T_GE_W2 + r*64 + c] = w2;
        W[O_T_QW    + r*64 + c] = qw;
        W[O_T_KW    + r*64 + c] = kw;
        W[O_T_BDW1  + r*64 + c] = bw;
    }
    for (int i = t; i < 384; i += 256) {
        W[O_SCW + i] = ldin(sc_w, i, f32);
        W[O_SHW + i] = ldin(sh_w, i, f32);
    }
}

// ---------------- lr pipeline: one point per WAVE, lane = channel ----------------
// Inner 64x64 convs use the attn-q2 pattern: coalesced transposed-weight loads
// + __shfl broadcast of the input vector (proven since R4).
__global__ __launch_bounds__(256) void lr_kernel(
    const void* __restrict__ xyz_lr,
    const void* __restrict__ sft,
    const void* __restrict__ val,
    const float* __restrict__ W,
    __hip_bfloat16* __restrict__ Kt, __hip_bfloat16* __restrict__ Vt,
    float4* __restrict__ LR, const int* dflag)
{
    const int f32 = *dflag;
    int lane = threadIdx.x & 63;
    int p = blockIdx.x * 4 + (threadIdx.x >> 6);   // 0..8191
    int b = p >> 12, m = p & (M_ - 1);
    size_t base = (size_t)b*3*M_ + m;
    float x = ldin(xyz_lr, base, f32), y = ldin(xyz_lr, base + M_, f32), z = ldin(xyz_lr, base + 2*M_, f32);
    if (lane == 0) LR[p] = make_float4(x, y, z, norm3np(x, y, z));

    // h_lane = relu(ge_w1[lane]·xyz + b1[lane])
    const float* w1 = W + O_GE_W1 + lane*3;
    float h = fmaxf(fmaf(w1[2], z, fmaf(w1[1], y, fmaf(w1[0], x, W[O_GE_B1 + lane]))), 0.f);
    // g_lane = ge_b2[lane] + sum_i W2[lane][i] * h_i  (WT coalesced + shfl bcast)
    float g = W[O_GE_B2 + lane];
#pragma unroll
    for (int i = 0; i < 64; ++i) {
        g = fmaf(W[O_T_GE_W2 + i*64 + lane], __shfl(h, i, 64), g);
    }
    // modulation
    float sc = W[O_SCB + lane], sh = W[O_SHB + lane];
    const float* wsc = W + O_SCW + lane*6;
    const float* wsh = W + O_SHW + lane*6;
#pragma unroll
    for (int d = 0; d < 6; ++d) {
        float s6 = ldin(sft, (size_t)b*6*M_ + d*M_ + m, f32);   // wave-uniform
        sc = fmaf(wsc[d], s6, sc); sh = fmaf(wsh[d], s6, sh);
    }
    float mod = fmaf(g, sc + 1.f, sh);
    // K_lane = kb[lane] + sum_i KW[lane][i] * mod_i
    float k = W[O_KB + lane];
#pragma unroll
    for (int i = 0; i < 64; ++i) {
        k = fmaf(W[O_T_KW + i*64 + lane], __shfl(mod, i, 64), k);
    }
    Kt[(size_t)p*64 + lane] = __float2bfloat16(k);
    // V transpose: lane=channel gather (stride-M read, coalesced write)
    Vt[(size_t)p*64 + lane] = __float2bfloat16(ldin(val, (size_t)b*64*M_ + (size_t)lane*M_ + m, f32));
}

// ---------------- hr pipeline: one point per WAVE, lane = channel ----------------
__global__ __launch_bounds__(256) void hr_kernel(
    const void* __restrict__ xyz_hr,
    const float* __restrict__ W,
    __hip_bfloat16* __restrict__ Q,
    void* __restrict__ out, const int* dflag)
{
    const int f32 = *dflag;
    int lane = threadIdx.x & 63;
    int p = blockIdx.x * 4 + (threadIdx.x >> 6);   // 0..32767
    int b = p >> 14, n = p & (N_ - 1);
    size_t base = (size_t)b*3*N_ + n;
    float x = ldin(xyz_hr, base, f32), y = ldin(xyz_hr, base + N_, f32), z = ldin(xyz_hr, base + 2*N_, f32);

    const float* w1 = W + O_GE_W1 + lane*3;
    float h = fmaxf(fmaf(w1[2], z, fmaf(w1[1], y, fmaf(w1[0], x, W[O_GE_B1 + lane]))), 0.f);
    float g = W[O_GE_B2 + lane];
#pragma unroll
    for (int i = 0; i < 64; ++i) {
        g = fmaf(W[O_T_GE_W2 + i*64 + lane], __shfl(h, i, 64), g);
    }
    // Q_lane
    float q = W[O_QB + lane];
#pragma unroll
    for (int i = 0; i < 64; ++i) {
        q = fmaf(W[O_T_QW + i*64 + lane], __shfl(g, i, 64), q);
    }
    Q[(size_t)p*64 + lane] = __float2bfloat16(q);
    // boundary head: hbd_lane = relu(bdw1[lane]·g + bdb1[lane]); o = sum bdw2*hbd + b2
    float hb = W[O_BDB1 + lane];
#pragma unroll
    for (int i = 0; i < 64; ++i) {
        hb = fmaf(W[O_T_BDW1 + i*64 + lane], __shfl(g, i, 64), hb);
    }
    float o = W[O_BDW2 + lane] * fmaxf(hb, 0.f);
#pragma unroll
    for (int sh = 1; sh < 64; sh <<= 1) o += __shfl_xor(o, sh, 64);
    if (lane == 0) {
        o += W[O_BDB2];
        stout(out, (size_t)B_*64*N_ + (size_t)b*N_ + n, 1.f / (1.f + __expf(-o)), f32);
    }
}

// lexicographic (d, i) compare-exchange: keep smaller at position a
#define CE(da, ia, db, ib) { \
    bool sw_ = (db < da) || (db == da && ib < ia); \
    float td_ = da; int ti_ = ia; \
    da = sw_ ? db : da; ia = sw_ ? ib : ia; \
    db = sw_ ? td_ : db; ib = sw_ ? ti_ : ib; }

// insert (d2, m) into the sorted-16 list if it beats the tail (lex order) [proven R10]
__device__ __forceinline__ void topk_insert(float (&bd)[16], int (&bi)[16], float d2, int m) {
    if (d2 < bd[15] || (d2 == bd[15] && m < bi[15])) {
        bd[15] = d2; bi[15] = m;
#pragma unroll
        for (int j = 15; j > 0; --j) CE(bd[j-1], bi[j-1], bd[j], bi[j]);
    }
}

// ---------------- kNN (R17 verbatim, proven 158us) ----------------
__global__ __launch_bounds__(256, 2) void knn_kernel(
    const void* __restrict__ xyz_hr,
    const float4* __restrict__ LR,
    unsigned short* __restrict__ kidx, const int* dflag)
{
#pragma clang fp reassociate(off)
    __shared__ float4         sLR[512];           //  8 KiB chunk of LR
    __shared__ float          sdd[256 * CAPS];    // 13.3 KiB, per-lane private d2
    __shared__ unsigned short sii[256 * CAPS];    //  6.7 KiB, per-lane private idx
    const int f32 = *dflag;
    int lane = threadIdx.x & 63;
    int p = blockIdx.x * 4 + (threadIdx.x >> 6);     // 0..32767, one point per wave
    int b = p >> 14, n = p & (N_ - 1);               // b is block-uniform
    size_t base = (size_t)b*3*N_ + n;
    float x = ldin(xyz_hr, base, f32), y = ldin(xyz_hr, base + N_, f32), z = ldin(xyz_hr, base + 2*N_, f32);
    float hn = norm3np(x, y, z);
    const float4* L = LR + b*M_;

    float d2r[64];
    float v = 3.4e38f;
#pragma unroll
    for (int c = 0; c < 8; ++c) {
        __syncthreads();
        sLR[threadIdx.x]       = L[c*512 + threadIdx.x];
        sLR[256 + threadIdx.x] = L[c*512 + 256 + threadIdx.x];
        __syncthreads();
#pragma unroll
        for (int i = 0; i < 8; ++i) {
            float d2 = d2np(x, y, z, hn, sLR[i*64 + lane]);
            d2r[c*8 + i] = d2;
            v = fminf(v, d2);
        }
    }
    v = fminf(v, __shfl_xor(v, 16, 64));
    v = fminf(v, __shfl_xor(v, 32, 64));
    float tau = v;
#pragma unroll
    for (int st = 1; st <= 8; st <<= 1) tau = fmaxf(tau, __shfl_xor(tau, st, 64));

    int sl = threadIdx.x * CAPS;
    int cnt = 0;
#pragma unroll
    for (int i = 0; i < 64; ++i) {
        if (d2r[i] <= tau) {
            if (cnt < CAP) { sdd[sl + cnt] = d2r[i]; sii[sl + cnt] = (unsigned short)(i*64 + lane); }
            cnt++;
        }
    }
    int bad = (cnt > CAP) ? 1 : 0;
#pragma unroll
    for (int st = 1; st <= 32; st <<= 1) bad |= __shfl_xor(bad, st, 64);
    if (bad) {
        float bd[16]; int bi[16];
#pragma unroll
        for (int j = 0; j < 16; ++j) { bd[j] = 3.4e38f; bi[j] = 0x7fffffff; }
        for (int m = 0; m < M_; ++m) {
            topk_insert(bd, bi, d2np(x, y, z, hn, L[m]), m);
        }
        if (lane == 0) {
            unsigned short* kr = kidx + (size_t)p*16;
#pragma unroll
            for (int j = 0; j < 16; ++j) kr[j] = (unsigned short)bi[j];
        }
        return;
    }
    for (int a = 0; a < cnt - 1; ++a) {
        float bv = sdd[sl + a]; int bm = (int)sii[sl + a]; int bj = a;
        for (int j2 = a + 1; j2 < cnt; ++j2) {
            float dj = sdd[sl + j2]; int mj = (int)sii[sl + j2];
            if (dj < bv || (dj == bv && mj < bm)) { bv = dj; bm = mj; bj = j2; }
        }
        float ta = sdd[sl + a]; int ia = (int)sii[sl + a];
        sdd[sl + a] = bv; sii[sl + a] = (unsigned short)bm;
        sdd[sl + bj] = ta; sii[sl + bj] = (unsigned short)ia;
    }

    int ptr = 0;
    for (int r = 0; r < 16; ++r) {
        float hd = 3.4e38f; int hi = 0x7fffffff;
        if (ptr < cnt) { hd = sdd[sl + ptr]; hi = (int)sii[sl + ptr]; }
        float md = hd; int mi = hi;
#pragma unroll
        for (int st = 1; st <= 32; st <<= 1) {
            float od = __shfl_xor(md, st, 64);
            int   oi = __shfl_xor(mi, st, 64);
            bool s = (od < md) || (od == md && oi < mi);
            md = s ? od : md; mi = s ? oi : mi;
        }
        if (ptr < cnt && hi == mi) {
            kidx[(size_t)p*16 + r] = (unsigned short)mi;
            ptr++;
        }
    }
}

// ---------------- attention (R17 verbatim) ----------------
__global__ __launch_bounds__(256) void attn_kernel(
    const void* __restrict__ xyz_hr,
    const float4* __restrict__ LR,
    const float* __restrict__ W,
    const __hip_bfloat16* __restrict__ Q,
    const __hip_bfloat16* __restrict__ Kt,
    const __hip_bfloat16* __restrict__ Vt,
    const unsigned short* __restrict__ kidx,
    void* __restrict__ out, const int* dflag)
{
    const int f32 = *dflag;
    int p = (blockIdx.x * 256 + threadIdx.x) >> 6;     // 0..32767, one point per wave
    int lane = threadIdx.x & 63;
    float fw0 = W[O_RPW1 + lane*3], fw1 = W[O_RPW1 + lane*3 + 1], fw2 = W[O_RPW1 + lane*3 + 2];
    float fb  = W[O_RPB1 + lane];

    int b = p >> 14, n = p & (N_ - 1);
    size_t base = (size_t)b*3*N_ + n;
    float xh = ldin(xyz_hr, base, f32), yh = ldin(xyz_hr, base + N_, f32), zh = ldin(xyz_hr, base + 2*N_, f32);
    float qc = b2f(Q[(size_t)p*64 + lane]);
    float q2 = 0.f;
#pragma unroll
    for (int cc = 0; cc < 64; ++cc) {
        float qb = __shfl(qc, cc, 64);
        q2 = fmaf(W[O_RPW2 + cc*64 + lane], qb, q2);
    }
    int idxv = (int)kidx[(size_t)p*16 + (lane & 15)];
    const float4* L = LR + b*M_;
    const __hip_bfloat16* Ktb = Kt + (size_t)b*M_*64;
    const __hip_bfloat16* Vtb = Vt + (size_t)b*M_*64;
    float lg[16];
#pragma unroll
    for (int j = 0; j < 16; ++j) {
        int mj = __shfl(idxv, j, 64);
        mj = (mj < M_) ? mj : (M_ - 1);
        float4 pl = L[mj];
        float r0 = xh - pl.x, r1 = yh - pl.y, r2 = zh - pl.z;
        float pe = fmaxf(fmaf(fw2, r2, fmaf(fw1, r1, fmaf(fw0, r0, fb))), 0.f);
        float v = fmaf(qc, b2f(Ktb[(size_t)mj*64 + lane]), q2 * pe);
#pragma unroll
        for (int sh = 1; sh < 64; sh <<= 1) v += __shfl_xor(v, sh, 64);
        lg[j] = v * 0.125f;
    }
    float mx = lg[0];
#pragma unroll
    for (int j = 1; j < 16; ++j) mx = fmaxf(mx, lg[j]);
    float sum = 0.f;
#pragma unroll
    for (int j = 0; j < 16; ++j) { lg[j] = __expf(lg[j] - mx); sum += lg[j]; }
    float inv = 1.f / sum;
    float o = 0.f;
#pragma unroll
    for (int j = 0; j < 16; ++j) {
        int mj = __shfl(idxv, j, 64);
        mj = (mj < M_) ? mj : (M_ - 1);
        o = fmaf(lg[j] * inv, b2f(Vtb[(size_t)mj*64 + lane]), o);
    }
    stout(out, ((size_t)(b*64 + lane))*N_ + n, o, f32);
}

// ---------------- launch ----------------
extern "C" void kernel_launch(void* const* d_in, const int* in_sizes, int n_in,
                              void* d_out, int out_size, void* d_ws, size_t ws_size,
                              hipStream_t stream) {
    const void* xyz_hr = d_in[0];
    const void* xyz_lr = d_in[1];
    const void* sft    = d_in[2];
    const void* val    = d_in[3];

    char* ws = (char*)d_ws;
    float* W  = (float*)ws;
    float4* LR = (float4*)(ws + OB_LR);
    __hip_bfloat16* Qp = (__hip_bfloat16*)(ws + OB_Q);
    __hip_bfloat16* Kt = (__hip_bfloat16*)(ws + OB_KT);
    __hip_bfloat16* Vt = (__hip_bfloat16*)(ws + OB_VT);
    unsigned short* kidx = (unsigned short*)(ws + OB_KIDX);
    int* dflag = (int*)(ws + OB_DFLAG);

    prep_kernel<<<1, 256, 0, stream>>>(
        xyz_hr,
        d_in[4],  d_in[5],  d_in[6],  d_in[7],  d_in[8],  d_in[9],  d_in[10], d_in[11],
        d_in[12], d_in[13], d_in[14], d_in[15], d_in[16], d_in[17], d_in[18], d_in[19],
        d_in[20], d_in[21], d_in[22], d_in[23], d_in[24], d_in[25], d_in[26], d_in[27],
        d_in[28], d_in[29], d_in[30], d_in[31], d_in[32], d_in[33], d_in[34], d_in[35],
        W, dflag);
    lr_kernel<<<2048, 256, 0, stream>>>(xyz_lr, sft, val, W, Kt, Vt, LR, dflag);
    hr_kernel<<<8192, 256, 0, stream>>>(xyz_hr, W, Qp, d_out, dflag);
    knn_kernel<<<8192, 256, 0, stream>>>(xyz_hr, LR, kidx, dflag);
    attn_kernel<<<8192, 256, 0, stream>>>(xyz_hr, LR, W, Qp, Kt, Vt, kidx, d_out, dflag);
}